// Round 1
// baseline (246.366 us; speedup 1.0000x reference)
//
#include <hip/hip_runtime.h>
#include <hip/hip_bf16.h>

typedef __attribute__((ext_vector_type(8))) short s16x8;
typedef __attribute__((ext_vector_type(4))) float f32x4v;

#define NB 4
#define NS 4096
#define ND 64

// ---------------------------------------------------------------------------
// Projection kernel: computes
//   y=0: qp' = bf16( (q @ Wq^T + bq) * qw / 64 )   layout [b][s][d]
//   y=1: kp' = bf16( (k @ Wk^T + bk) * kw / 64 )   layout [b][s][d]
//   y=2: vT  = bf16( (v @ Wv^T + bv) )             layout [b][d][s]  (transposed)
// Thread-per-row fp32 VALU GEMM; W rows read as uniform (scalarized) loads.
// ---------------------------------------------------------------------------
__global__ __launch_bounds__(256) void proj_kernel(
    const float* __restrict__ q, const float* __restrict__ k, const float* __restrict__ v,
    const float* __restrict__ Wq, const float* __restrict__ bq,
    const float* __restrict__ Wk, const float* __restrict__ bk,
    const float* __restrict__ Wv, const float* __restrict__ bv,
    const float* __restrict__ qw, const float* __restrict__ kw,
    __hip_bfloat16* __restrict__ qpo, __hip_bfloat16* __restrict__ kpo,
    __hip_bfloat16* __restrict__ vTo)
{
    const int which = blockIdx.y;
    const int row = blockIdx.x * 256 + threadIdx.x;      // 0..16383 = b*4096+s
    const float* X    = (which == 0) ? q  : (which == 1) ? k  : v;
    const float* W    = (which == 0) ? Wq : (which == 1) ? Wk : Wv;
    const float* bias = (which == 0) ? bq : (which == 1) ? bk : bv;

    float x[64];
    const float4* xr = (const float4*)(X + (size_t)row * 64);
    #pragma unroll
    for (int i = 0; i < 16; ++i) ((float4*)x)[i] = xr[i];

    const int b = row >> 12, s = row & 4095;

    for (int d = 0; d < 64; ++d) {
        float acc = 0.f;
        const float4* wr = (const float4*)(W + d * 64);
        #pragma unroll
        for (int i = 0; i < 16; ++i) {
            float4 w = wr[i];
            acc += x[4*i+0]*w.x + x[4*i+1]*w.y + x[4*i+2]*w.z + x[4*i+3]*w.w;
        }
        acc += bias[d];
        if (which == 0) {
            qpo[(size_t)row*64 + d] = __float2bfloat16(acc * qw[d] * 0.015625f);
        } else if (which == 1) {
            kpo[(size_t)row*64 + d] = __float2bfloat16(acc * kw[d] * 0.015625f);
        } else {
            vTo[((size_t)b*64 + d)*4096 + s] = __float2bfloat16(acc);
        }
    }
}

// ---------------------------------------------------------------------------
// Flash-attention kernel. Block = 64 q-rows (4 waves x 16 rows), KV-tile = 64.
// mfma_f32_16x16x32_bf16. Mask ignored (scalar, softmax shift-invariant).
// Scale (qw/d, kw/d) pre-folded into qp'/kp'.
// C/D layout: col = lane&15, row = 4*(lane>>4)+reg  (m89-verified).
// A/B frag:   row = lane&15, k  = 8*(lane>>4)+j (contiguous 16B).
// ---------------------------------------------------------------------------
__global__ __launch_bounds__(256) void attn_kernel(
    const __hip_bfloat16* __restrict__ qp, const __hip_bfloat16* __restrict__ kp,
    const __hip_bfloat16* __restrict__ vT, float* __restrict__ out)
{
    __shared__ __hip_bfloat16 Klds[64][72];        // [t][d], +8 pad (bank fix)
    __shared__ __hip_bfloat16 Vlds[64][72];        // [d][t], +8 pad
    __shared__ __hip_bfloat16 Plds[4][16][72];     // per-wave P transpose buffer

    const int tid  = threadIdx.x;
    const int wave = tid >> 6, lane = tid & 63;
    const int g    = lane >> 4, r16 = lane & 15;
    const int b    = blockIdx.x;                   // fast dim -> XCD i serves one batch
    const int qt   = blockIdx.y;

    // Q fragments, register-resident for the whole kernel
    const __hip_bfloat16* qbase = qp + ((size_t)(b*4096 + qt*64 + wave*16 + r16)) * 64;
    s16x8 aQ[2];
    aQ[0] = *(const s16x8*)(qbase + 8*g);
    aQ[1] = *(const s16x8*)(qbase + 32 + 8*g);

    float mrow[4], lrow[4];
    f32x4v O[4];
    #pragma unroll
    for (int i = 0; i < 4; ++i) { mrow[i] = -1e30f; lrow[i] = 0.f; O[i] = (f32x4v)0.f; }

    const int srow = tid >> 3;            // 0..31  (staging row)
    const int scol = (tid & 7) * 8;       // 0..56  (staging col, 8 bf16 = 16B)

    const __hip_bfloat16* kbB = kp + (size_t)(b*4096) * 64;
    const __hip_bfloat16* vbB = vT + (size_t)(b*64) * 4096;

    for (int kv = 0; kv < 64; ++kv) {
        __syncthreads();
        // stage K-tile [64 t][64 d] and V-tile [64 d][64 t] (coalesced 16B)
        #pragma unroll
        for (int p = 0; p < 2; ++p) {
            int r = srow + 32*p;
            *(s16x8*)(&Klds[r][scol]) = *(const s16x8*)(kbB + (size_t)(kv*64 + r)*64 + scol);
            *(s16x8*)(&Vlds[r][scol]) = *(const s16x8*)(vbB + (size_t)r*4096 + kv*64 + scol);
        }
        __syncthreads();

        // ---- QK^T: S[16 q][64 t] per wave ----
        f32x4v acc[4];
        #pragma unroll
        for (int nt = 0; nt < 4; ++nt) {
            acc[nt] = (f32x4v)0.f;
            #pragma unroll
            for (int c = 0; c < 2; ++c) {
                s16x8 bK = *(const s16x8*)(&Klds[r16 + 16*nt][32*c + 8*g]);
                acc[nt] = __builtin_amdgcn_mfma_f32_16x16x32_bf16(aQ[c], bK, acc[nt], 0, 0, 0);
            }
        }

        // ---- online softmax (row = 4*g+reg, spread over 16 lanes) ----
        float fac[4];
        #pragma unroll
        for (int reg = 0; reg < 4; ++reg) {
            float mx = fmaxf(fmaxf(acc[0][reg], acc[1][reg]),
                             fmaxf(acc[2][reg], acc[3][reg]));
            #pragma unroll
            for (int d = 1; d < 16; d <<= 1) mx = fmaxf(mx, __shfl_xor(mx, d));
            float mn = fmaxf(mrow[reg], mx);
            fac[reg] = __expf(mrow[reg] - mn);
            mrow[reg] = mn;
        }
        float rs[4] = {0.f, 0.f, 0.f, 0.f};
        #pragma unroll
        for (int nt = 0; nt < 4; ++nt) {
            #pragma unroll
            for (int reg = 0; reg < 4; ++reg) {
                float pv = __expf(acc[nt][reg] - mrow[reg]);
                acc[nt][reg] = pv;
                rs[reg] += pv;
            }
        }
        #pragma unroll
        for (int reg = 0; reg < 4; ++reg) {
            float r = rs[reg];
            #pragma unroll
            for (int d = 1; d < 16; d <<= 1) r += __shfl_xor(r, d);
            lrow[reg] = lrow[reg] * fac[reg] + r;
            O[0][reg] *= fac[reg]; O[1][reg] *= fac[reg];
            O[2][reg] *= fac[reg]; O[3][reg] *= fac[reg];
        }

        // ---- P -> LDS (transpose C-layout -> A-layout), per-wave private ----
        #pragma unroll
        for (int nt = 0; nt < 4; ++nt)
            #pragma unroll
            for (int reg = 0; reg < 4; ++reg)
                Plds[wave][4*g + reg][r16 + 16*nt] = __float2bfloat16(acc[nt][reg]);

        // ---- PV: O[16 q][64 d] += P[16 q][64 t] * V[64 t][64 d] ----
        #pragma unroll
        for (int c = 0; c < 2; ++c) {
            s16x8 aP = *(const s16x8*)(&Plds[wave][r16][32*c + 8*g]);
            #pragma unroll
            for (int nt = 0; nt < 4; ++nt) {
                s16x8 bV = *(const s16x8*)(&Vlds[r16 + 16*nt][32*c + 8*g]);
                O[nt] = __builtin_amdgcn_mfma_f32_16x16x32_bf16(aP, bV, O[nt], 0, 0, 0);
            }
        }
    }

    // ---- epilogue: divide by l, write fp32 ----
    float* orow = out + ((size_t)(b*4096 + qt*64 + wave*16 + 4*g)) * 64;
    #pragma unroll
    for (int reg = 0; reg < 4; ++reg) {
        float inv = 1.f / lrow[reg];
        #pragma unroll
        for (int nt = 0; nt < 4; ++nt)
            orow[(size_t)reg*64 + r16 + 16*nt] = O[nt][reg] * inv;
    }
}

extern "C" void kernel_launch(void* const* d_in, const int* in_sizes, int n_in,
                              void* d_out, int out_size, void* d_ws, size_t ws_size,
                              hipStream_t stream) {
    (void)in_sizes; (void)n_in; (void)out_size; (void)ws_size;
    const float* q  = (const float*)d_in[0];
    const float* k  = (const float*)d_in[1];
    const float* v  = (const float*)d_in[2];
    // d_in[3] = attn_mask (1,1,1): scalar added to all scores -> softmax no-op
    const float* Wq = (const float*)d_in[4];
    const float* bq = (const float*)d_in[5];
    const float* Wk = (const float*)d_in[6];
    const float* bk = (const float*)d_in[7];
    const float* Wv = (const float*)d_in[8];
    const float* bv = (const float*)d_in[9];
    const float* qw = (const float*)d_in[10];
    const float* kw = (const float*)d_in[11];

    __hip_bfloat16* qpb = (__hip_bfloat16*)d_ws;            // 2 MB
    __hip_bfloat16* kpb = qpb + (size_t)NB*NS*ND;           // 2 MB
    __hip_bfloat16* vTb = kpb + (size_t)NB*NS*ND;           // 2 MB

    proj_kernel<<<dim3(64, 3), 256, 0, stream>>>(q, k, v, Wq, bq, Wk, bk, Wv, bv,
                                                 qw, kw, qpb, kpb, vTb);
    attn_kernel<<<dim3(NB, NS/64), 256, 0, stream>>>(qpb, kpb, vTb, (float*)d_out);
}

// Round 3
// 192.913 us; speedup vs baseline: 1.2771x; 1.2771x over previous
//
#include <hip/hip_runtime.h>
#include <hip/hip_bf16.h>

typedef __attribute__((ext_vector_type(8)))  short    s16x8;
typedef __attribute__((ext_vector_type(16))) float    f32x16;
typedef __attribute__((ext_vector_type(4)))  unsigned u32x4;

#define NB 4
#define NS 4096
#define ND 64
#define NTOK (NB*NS)

static __device__ __forceinline__ unsigned cvt_pk_bf16(float lo, float hi) {
    unsigned r;
    asm("v_cvt_pk_bf16_f32 %0, %1, %2" : "=v"(r) : "v"(lo), "v"(hi));
    return r;
}
static __device__ __forceinline__ short f2bf_s(float x) {
    __hip_bfloat16 h = __float2bfloat16(x);
    return (short)__builtin_bit_cast(unsigned short, h);
}

// ---------------------------------------------------------------------------
// Projection: y=0: qp' = bf16((q@Wq^T+bq)*qw/64) [b][s][d]
//             y=1: kp' = bf16((k@Wk^T+bk)*kw/64) [b][s][d]
//             y=2: vT  = bf16( v@Wv^T+bv )       [b][d][s] (transposed)
// 512 threads = 8 waves; wave w computes outputs d=8w..8w+7 for 64 rows
// (row = bx*64 + lane). W-row addresses are wave-uniform -> s_loads.
// 8 independent FMA chains per thread; 6144 waves total (24/CU).
// ---------------------------------------------------------------------------
__global__ __launch_bounds__(512) void proj_kernel(
    const float* __restrict__ q, const float* __restrict__ k, const float* __restrict__ v,
    const float* __restrict__ Wq, const float* __restrict__ bq,
    const float* __restrict__ Wk, const float* __restrict__ bk,
    const float* __restrict__ Wv, const float* __restrict__ bv,
    const float* __restrict__ qw, const float* __restrict__ kw,
    __hip_bfloat16* __restrict__ qpo, __hip_bfloat16* __restrict__ kpo,
    __hip_bfloat16* __restrict__ vTo)
{
    const int which = blockIdx.y;
    const int wv    = threadIdx.x >> 6;                 // out-group 0..7
    const int lane  = threadIdx.x & 63;
    const int row   = blockIdx.x * 64 + lane;           // b*4096+s
    const float* X    = (which == 0) ? q  : (which == 1) ? k  : v;
    const float* W    = (which == 0) ? Wq : (which == 1) ? Wk : Wv;
    const float* bias = (which == 0) ? bq : (which == 1) ? bk : bv;
    const float* sc   = (which == 0) ? qw : kw;

    float x[64];
    const float4* xr = (const float4*)(X + (size_t)row * ND);
    #pragma unroll
    for (int i = 0; i < 16; ++i) ((float4*)x)[i] = xr[i];

    float acc8[8];
    #pragma unroll
    for (int dd = 0; dd < 8; ++dd) {
        const float4* wr = (const float4*)(W + (8*wv + dd) * ND);
        float s = 0.f;
        #pragma unroll
        for (int i = 0; i < 16; ++i) {
            float4 w = wr[i];
            s += x[4*i]*w.x + x[4*i+1]*w.y + x[4*i+2]*w.z + x[4*i+3]*w.w;
        }
        acc8[dd] = s + bias[8*wv + dd];
    }

    if (which == 2) {
        const int bb = row >> 12, ss = row & (NS - 1);
        #pragma unroll
        for (int dd = 0; dd < 8; ++dd)
            vTo[((size_t)bb*ND + 8*wv + dd)*NS + ss] = __float2bfloat16(acc8[dd]);
    } else {
        __hip_bfloat16* dst = ((which == 0) ? qpo : kpo) + (size_t)row * ND;
        s16x8 vch;
        #pragma unroll
        for (int j = 0; j < 8; ++j)
            vch[j] = f2bf_s(acc8[j] * sc[8*wv + j] * 0.015625f);
        *(s16x8*)(dst + 8*wv) = vch;
    }
}

// ---------------------------------------------------------------------------
// Flash attention, 1 wave per (32 q-rows, KV-split), ZERO LDS, ZERO barriers.
// Swapped QK^T: S^T[t][q] = K_tile . Q^T  (A=K rows t, B=Q cols q=lane&31).
// 32x32x16 layouts: A row=lane&31,k=8*hi+j; B col=lane&31,k=8*hi+j;
//                   C/D col=lane&31, row=(reg&3)+8*(reg>>2)+4*hi.
// Softmax: lane owns q=lane&31 -> reg-tree max + one shfl_xor(32).
// P packed to bf16 via cvt_pk + permlane32_swap (in-register transpose
// straight into PV B-fragments). PV: O^T[d][q] = V^T . P^T.
// K,V read straight from L2 (1MB KV per batch, batch pinned per XCD, bid&3).
// Grid = 512*nsplit blocks: b=bid&3, qwi=(bid>>2)&127, split=bid>>9.
// ---------------------------------------------------------------------------
__global__ __launch_bounds__(64) void attn_kernel(
    const __hip_bfloat16* __restrict__ qp, const __hip_bfloat16* __restrict__ kp,
    const __hip_bfloat16* __restrict__ vT,
    float* __restrict__ opart, float* __restrict__ mpart, float* __restrict__ lpart,
    float* __restrict__ outdirect, int nsplit)
{
    const int lane = threadIdx.x;
    const int r31 = lane & 31, hi = lane >> 5;
    int bid = blockIdx.x;
    const int b     = bid & 3;
    const int qwi   = (bid >> 2) & 127;                 // 128 q-waves per batch
    const int split = bid >> 9;
    const int qrow  = qwi * 32 + r31;                   // 0..4095

    // Q fragments (B-operand): Q[q=lane&31][d=16c+8hi+j]
    const __hip_bfloat16* qr = qp + ((size_t)b*NS + qrow) * ND + 8*hi;
    s16x8 bQ[4];
    #pragma unroll
    for (int c = 0; c < 4; ++c) bQ[c] = *(const s16x8*)(qr + 16*c);

    const __hip_bfloat16* kb = kp + (size_t)b*NS*ND;
    const __hip_bfloat16* vb = vT + (size_t)b*ND*NS;

    f32x16 O0 = (f32x16)0.f, O1 = (f32x16)0.f;          // O^T, d-halves
    float m = -1e30f, l = 0.f;

    const int span  = NS / nsplit;
    const int tbeg  = split * span;
    const int iters = span >> 6;

    for (int it = 0; it < iters; ++it) {
        const int tb = tbeg + (it << 6);

        // ---- QK^T: two 32-row t-tiles, K=64 over 4 mfmas each ----
        const __hip_bfloat16* k0 = kb + ((size_t)tb + r31) * ND + 8*hi;
        f32x16 s0 = (f32x16)0.f, s1 = (f32x16)0.f;
        #pragma unroll
        for (int c = 0; c < 4; ++c) {
            s16x8 a0 = *(const s16x8*)(k0 + 16*c);
            s16x8 a1 = *(const s16x8*)(k0 + 32*ND + 16*c);
            s0 = __builtin_amdgcn_mfma_f32_32x32x16_bf16(a0, bQ[c], s0, 0, 0, 0);
            s1 = __builtin_amdgcn_mfma_f32_32x32x16_bf16(a1, bQ[c], s1, 0, 0, 0);
        }

        // ---- online softmax: q = lane&31; t = 32*tile + (r&3)+8*(r>>2)+4*hi
        float mx = s0[0];
        #pragma unroll
        for (int r = 1; r < 16; ++r) mx = fmaxf(mx, s0[r]);
        #pragma unroll
        for (int r = 0; r < 16; ++r) mx = fmaxf(mx, s1[r]);
        mx = fmaxf(mx, __shfl_xor(mx, 32));
        const float mn  = fmaxf(m, mx);
        const float fac = __expf(m - mn);
        m = mn;
        float rs = 0.f;
        #pragma unroll
        for (int r = 0; r < 16; ++r) { s0[r] = __expf(s0[r] - mn); rs += s0[r]; }
        #pragma unroll
        for (int r = 0; r < 16; ++r) { s1[r] = __expf(s1[r] - mn); rs += s1[r]; }
        rs += __shfl_xor(rs, 32);
        l = l * fac + rs;
        #pragma unroll
        for (int r = 0; r < 16; ++r) { O0[r] *= fac; O1[r] *= fac; }

        // ---- pack P -> bf16 dwords; permlane32_swap pairs (u=2k1, 2k1+1)
        //      -> B-frag(ks=2*tile+k1) dwords [x0',x1',y0',y1'] ----
        unsigned pw0[2][4], pw1[2][4];
        #pragma unroll
        for (int u = 0; u < 4; ++u) {
            pw0[0][u] = cvt_pk_bf16(s0[4*u],   s0[4*u+1]);
            pw1[0][u] = cvt_pk_bf16(s0[4*u+2], s0[4*u+3]);
            pw0[1][u] = cvt_pk_bf16(s1[4*u],   s1[4*u+1]);
            pw1[1][u] = cvt_pk_bf16(s1[4*u+2], s1[4*u+3]);
        }

        // ---- PV: O^T[d][q] += V^T . P^T ----
        const __hip_bfloat16* vp = vb + (size_t)r31 * NS + tb + 8*hi;
        #pragma unroll
        for (int ks = 0; ks < 4; ++ks) {
            const int tl = ks >> 1, k1 = ks & 1;
            unsigned x0 = pw0[tl][2*k1], y0 = pw0[tl][2*k1 + 1];
            unsigned x1 = pw1[tl][2*k1], y1 = pw1[tl][2*k1 + 1];
            asm("v_permlane32_swap_b32 %0, %1" : "+v"(x0), "+v"(y0));
            asm("v_permlane32_swap_b32 %0, %1" : "+v"(x1), "+v"(y1));
            u32x4 fv = {x0, x1, y0, y1};
            s16x8 bP = __builtin_bit_cast(s16x8, fv);
            s16x8 a0 = *(const s16x8*)(vp + 16*ks);
            s16x8 a1 = *(const s16x8*)(vp + (size_t)32*NS + 16*ks);
            O0 = __builtin_amdgcn_mfma_f32_32x32x16_bf16(a0, bP, O0, 0, 0, 0);
            O1 = __builtin_amdgcn_mfma_f32_32x32x16_bf16(a1, bP, O1, 0, 0, 0);
        }
    }

    // ---- epilogue: O^T rows d = 8u+4hi+{0..3} (+32 for O1), col q=lane&31
    const size_t gq = (size_t)b*NS + qrow;
    if (outdirect) {
        const float invl = 1.f / l;
        float* orow = outdirect + gq * ND;
        #pragma unroll
        for (int u = 0; u < 4; ++u) {
            const int d0 = 8*u + 4*hi;
            float4 w0v = {O0[4*u]*invl, O0[4*u+1]*invl, O0[4*u+2]*invl, O0[4*u+3]*invl};
            *(float4*)(orow + d0) = w0v;
            float4 w1v = {O1[4*u]*invl, O1[4*u+1]*invl, O1[4*u+2]*invl, O1[4*u+3]*invl};
            *(float4*)(orow + d0 + 32) = w1v;
        }
    } else {
        float* prow = opart + ((size_t)split*NTOK + gq) * ND;
        #pragma unroll
        for (int u = 0; u < 4; ++u) {
            const int d0 = 8*u + 4*hi;
            float4 w0v = {O0[4*u], O0[4*u+1], O0[4*u+2], O0[4*u+3]};
            *(float4*)(prow + d0) = w0v;
            float4 w1v = {O1[4*u], O1[4*u+1], O1[4*u+2], O1[4*u+3]};
            *(float4*)(prow + d0 + 32) = w1v;
        }
        if (lane < 32) {
            mpart[(size_t)split*NTOK + gq] = m;
            lpart[(size_t)split*NTOK + gq] = l;
        }
    }
}

// ---------------------------------------------------------------------------
// Combine KV-split partials: out = sum_s O_s*exp(m_s-M) / sum_s l_s*exp(m_s-M)
// ---------------------------------------------------------------------------
__global__ __launch_bounds__(256) void combine_kernel(
    const float* __restrict__ opart, const float* __restrict__ mpart,
    const float* __restrict__ lpart, float* __restrict__ out, int nsplit)
{
    const int tid = threadIdx.x;
    const int r = blockIdx.x * 16 + (tid >> 4);
    const int c = (tid & 15) * 4;
    float ms[8];
    float M = -1e30f;
    #pragma unroll
    for (int s = 0; s < 8; ++s) {
        if (s >= nsplit) break;
        ms[s] = mpart[(size_t)s*NTOK + r];
        M = fmaxf(M, ms[s]);
    }
    float L = 0.f;
    float4 acc = {0.f, 0.f, 0.f, 0.f};
    #pragma unroll
    for (int s = 0; s < 8; ++s) {
        if (s >= nsplit) break;
        const float w = __expf(ms[s] - M);
        L += lpart[(size_t)s*NTOK + r] * w;
        float4 o = *(const float4*)(opart + ((size_t)s*NTOK + r)*ND + c);
        acc.x += o.x*w; acc.y += o.y*w; acc.z += o.z*w; acc.w += o.w*w;
    }
    const float inv = 1.f / L;
    float4 res = {acc.x*inv, acc.y*inv, acc.z*inv, acc.w*inv};
    *(float4*)(out + (size_t)r*ND + c) = res;
}

extern "C" void kernel_launch(void* const* d_in, const int* in_sizes, int n_in,
                              void* d_out, int out_size, void* d_ws, size_t ws_size,
                              hipStream_t stream) {
    (void)in_sizes; (void)n_in; (void)out_size;
    const float* q  = (const float*)d_in[0];
    const float* k  = (const float*)d_in[1];
    const float* v  = (const float*)d_in[2];
    // d_in[3] = attn_mask (1,1,1): scalar added to all scores -> softmax no-op
    const float* Wq = (const float*)d_in[4];
    const float* bq = (const float*)d_in[5];
    const float* Wk = (const float*)d_in[6];
    const float* bk = (const float*)d_in[7];
    const float* Wv = (const float*)d_in[8];
    const float* bv = (const float*)d_in[9];
    const float* qw = (const float*)d_in[10];
    const float* kw = (const float*)d_in[11];

    __hip_bfloat16* qpb = (__hip_bfloat16*)d_ws;            // 2 MB
    __hip_bfloat16* kpb = qpb + (size_t)NTOK*ND;            // 2 MB
    __hip_bfloat16* vTb = kpb + (size_t)NTOK*ND;            // 2 MB
    float* rest = (float*)(vTb + (size_t)NTOK*ND);

    auto need = [](int s) {
        return (size_t)NTOK*ND*2*3 + (size_t)s*NTOK*(ND*4 + 8);
    };
    const int nsplit = (ws_size >= need(8)) ? 8
                     : (ws_size >= need(4)) ? 4
                     : (ws_size >= need(2)) ? 2 : 1;

    float* opart = rest;
    float* mp = opart + (size_t)nsplit*NTOK*ND;
    float* lp = mp + (size_t)nsplit*NTOK;

    proj_kernel<<<dim3(256, 3), 512, 0, stream>>>(q, k, v, Wq, bq, Wk, bk, Wv, bv,
                                                  qw, kw, qpb, kpb, vTb);
    attn_kernel<<<dim3(512*nsplit), 64, 0, stream>>>(
        qpb, kpb, vTb, opart, mp, lp,
        (nsplit == 1) ? (float*)d_out : nullptr, nsplit);
    if (nsplit > 1)
        combine_kernel<<<dim3(NTOK/16), 256, 0, stream>>>(opart, mp, lp,
                                                          (float*)d_out, nsplit);
}

// Round 4
// 145.576 us; speedup vs baseline: 1.6924x; 1.3252x over previous
//
#include <hip/hip_runtime.h>
#include <hip/hip_bf16.h>

typedef __attribute__((ext_vector_type(8)))  short    s16x8;
typedef __attribute__((ext_vector_type(16))) float    f32x16;
typedef __attribute__((ext_vector_type(4)))  unsigned u32x4;

#define NB 4
#define NS 4096
#define ND 64
#define NTOK (NB*NS)
#define PERB (NS*ND)   // elements per batch per tensor

static __device__ __forceinline__ unsigned cvt_pk_bf16(float lo, float hi) {
    unsigned r;
    asm("v_cvt_pk_bf16_f32 %0, %1, %2" : "=v"(r) : "v"(lo), "v"(hi));
    return r;
}
static __device__ __forceinline__ float exp2_fast(float x) {
    float r;
    asm("v_exp_f32 %0, %1" : "=v"(r) : "v"(x));
    return r;
}
static __device__ __forceinline__ short f2bf_s(float x) {
    __hip_bfloat16 h = __float2bfloat16(x);
    return (short)__builtin_bit_cast(unsigned short, h);
}

// ---------------------------------------------------------------------------
// Projection into MFMA-fragment-major layouts (so attn does contiguous 1KB
// wave reads, zero LDS):
//  Q',K' (y=0,1): elem [t=32T+r][d=16c+8hi+j] -> T*2048 + (c*2+hi)*256 + r*8 + j
//     (proj thread owns row t, outs d=8wv..8wv+7 -> c*2+hi == wv, one 16B store,
//      coalesced 512B segments across lanes)
//  V^T  (y=2):   elem [d=32h+r][t=64TT+16ks+8hi+j]
//                -> TT*4096 + h*2048 + ks*512 + hi*256 + r*8 + j
//  Scales folded: Q' *= qw/64 * LOG2E (so attn uses v_exp_f32=2^x), K' *= kw/64.
// 512 threads = 8 waves; wave wv computes outs d=8wv..8wv+7 for rows bx*64+lane.
// ---------------------------------------------------------------------------
__global__ __launch_bounds__(512) void proj_kernel(
    const float* __restrict__ q, const float* __restrict__ k, const float* __restrict__ v,
    const float* __restrict__ Wq, const float* __restrict__ bq,
    const float* __restrict__ Wk, const float* __restrict__ bk,
    const float* __restrict__ Wv, const float* __restrict__ bv,
    const float* __restrict__ qw, const float* __restrict__ kw,
    __hip_bfloat16* __restrict__ qf, __hip_bfloat16* __restrict__ kf,
    __hip_bfloat16* __restrict__ vf)
{
    const int which = blockIdx.y;
    const int wv    = threadIdx.x >> 6;                 // out-group 0..7
    const int lane  = threadIdx.x & 63;
    const int row   = blockIdx.x * 64 + lane;           // b*4096+s
    const float* X    = (which == 0) ? q  : (which == 1) ? k  : v;
    const float* W    = (which == 0) ? Wq : (which == 1) ? Wk : Wv;
    const float* bias = (which == 0) ? bq : (which == 1) ? bk : bv;

    float x[64];
    const float4* xr = (const float4*)(X + (size_t)row * ND);
    #pragma unroll
    for (int i = 0; i < 16; ++i) ((float4*)x)[i] = xr[i];

    float acc8[8];
    #pragma unroll
    for (int dd = 0; dd < 8; ++dd) {
        const float4* wr = (const float4*)(W + (8*wv + dd) * ND);
        float s = 0.f;
        #pragma unroll
        for (int i = 0; i < 16; ++i) {
            float4 w = wr[i];
            s += x[4*i]*w.x + x[4*i+1]*w.y + x[4*i+2]*w.z + x[4*i+3]*w.w;
        }
        acc8[dd] = s + bias[8*wv + dd];
    }

    const int b = row >> 12, t = row & (NS - 1);

    if (which == 2) {
        // V^T frag-major: d = 8wv+dd -> h=wv>>2, r=8*(wv&3)+dd; t -> TT,ks,hi,j
        const size_t base = (size_t)b*PERB + (size_t)(t >> 6)*4096
                          + ((t >> 4) & 3)*512 + ((t >> 3) & 1)*256 + (t & 7)
                          + (wv >> 2)*2048;
        #pragma unroll
        for (int dd = 0; dd < 8; ++dd)
            vf[base + (8*(wv & 3) + dd)*8] = __float2bfloat16(acc8[dd]);
    } else {
        const float* sc = (which == 0) ? qw : kw;
        const float extra = (which == 0) ? 1.44269504088896f : 1.0f; // LOG2E
        s16x8 vch;
        #pragma unroll
        for (int j = 0; j < 8; ++j)
            vch[j] = f2bf_s(acc8[j] * sc[8*wv + j] * 0.015625f * extra);
        __hip_bfloat16* dst = ((which == 0) ? qf : kf)
            + (size_t)b*PERB + (size_t)(t >> 5)*2048 + wv*256 + (t & 31)*8;
        *(s16x8*)dst = vch;
    }
}

// ---------------------------------------------------------------------------
// Flash attention, 1 wave per (32 q-rows, KV-split). ZERO LDS/barriers.
// All K/Q/V fragment loads are contiguous 1KB wave reads (frag-major layout).
// Swapped QK^T: S^T[t][q] = K . Q^T. Softmax WITHOUT max subtraction
// (scores bounded |s|<~1 by the 1/d^2 scaling; LOG2E pre-folded into Q').
// P packed to bf16 via cvt_pk + permlane32_swap -> PV B-frags in-register.
// PV: O^T[d][q] = V^T . P^T. Grid: b=bid&3 (XCD-pinned), qwi=(bid>>2)&127,
// split=bid>>9.
// ---------------------------------------------------------------------------
__global__ __launch_bounds__(64, 4) void attn_kernel(
    const __hip_bfloat16* __restrict__ qf, const __hip_bfloat16* __restrict__ kf,
    const __hip_bfloat16* __restrict__ vf,
    float* __restrict__ opart, float* __restrict__ lpart,
    float* __restrict__ outdirect, int nsplit)
{
    const int lane = threadIdx.x;
    const int r31 = lane & 31, hi = lane >> 5;
    const int bid = blockIdx.x;
    const int b     = bid & 3;
    const int qwi   = (bid >> 2) & 127;                 // 128 q-waves per batch
    const int split = bid >> 9;

    const __hip_bfloat16* qb = qf + (size_t)b*PERB;
    const __hip_bfloat16* kb = kf + (size_t)b*PERB;
    const __hip_bfloat16* vb = vf + (size_t)b*PERB;

    // Q B-frags: contiguous 1KB per c
    const __hip_bfloat16* qr = qb + (size_t)qwi*2048 + hi*256 + r31*8;
    s16x8 bQ[4];
    #pragma unroll
    for (int c = 0; c < 4; ++c) bQ[c] = *(const s16x8*)(qr + c*512);

    f32x16 O0 = (f32x16)0.f, O1 = (f32x16)0.f;          // O^T, d-halves
    float l = 0.f;

    const int span  = NS / nsplit;
    const int tbeg  = split * span;
    const int iters = span >> 6;

    for (int it = 0; it < iters; ++it) {
        const int tb = tbeg + (it << 6);

        // ---- QK^T: two 32-row t-tiles, K=64 over 4 mfmas each ----
        const __hip_bfloat16* kbase = kb + (size_t)(tb >> 5)*2048 + hi*256 + r31*8;
        f32x16 s0 = (f32x16)0.f, s1 = (f32x16)0.f;
        #pragma unroll
        for (int c = 0; c < 4; ++c) {
            s16x8 a0 = *(const s16x8*)(kbase + c*512);
            s16x8 a1 = *(const s16x8*)(kbase + 2048 + c*512);
            s0 = __builtin_amdgcn_mfma_f32_32x32x16_bf16(a0, bQ[c], s0, 0, 0, 0);
            s1 = __builtin_amdgcn_mfma_f32_32x32x16_bf16(a1, bQ[c], s1, 0, 0, 0);
        }

        // ---- softmax sans max: p = 2^s (LOG2E folded into Q') ----
        #pragma unroll
        for (int r = 0; r < 16; ++r) { s0[r] = exp2_fast(s0[r]); s1[r] = exp2_fast(s1[r]); }
        // balanced-tree sum of 32 values
        float t0 = ((s0[0]+s0[1])+(s0[2]+s0[3])) + ((s0[4]+s0[5])+(s0[6]+s0[7]));
        float t1 = ((s0[8]+s0[9])+(s0[10]+s0[11])) + ((s0[12]+s0[13])+(s0[14]+s0[15]));
        float t2 = ((s1[0]+s1[1])+(s1[2]+s1[3])) + ((s1[4]+s1[5])+(s1[6]+s1[7]));
        float t3 = ((s1[8]+s1[9])+(s1[10]+s1[11])) + ((s1[12]+s1[13])+(s1[14]+s1[15]));
        float rs = (t0 + t1) + (t2 + t3);
        rs += __shfl_xor(rs, 32);
        l += rs;

        // ---- pack P -> bf16 dwords; permlane32_swap pairs (u=2k1, 2k1+1)
        //      -> B-frag(ks=2*tile+k1) dwords [x0',x1',y0',y1'] ----
        unsigned pw0[2][4], pw1[2][4];
        #pragma unroll
        for (int u = 0; u < 4; ++u) {
            pw0[0][u] = cvt_pk_bf16(s0[4*u],   s0[4*u+1]);
            pw1[0][u] = cvt_pk_bf16(s0[4*u+2], s0[4*u+3]);
            pw0[1][u] = cvt_pk_bf16(s1[4*u],   s1[4*u+1]);
            pw1[1][u] = cvt_pk_bf16(s1[4*u+2], s1[4*u+3]);
        }

        // ---- PV: O^T[d][q] += V^T . P^T  (V frags contiguous 1KB) ----
        const __hip_bfloat16* vbase = vb + (size_t)(tb >> 6)*4096 + hi*256 + r31*8;
        #pragma unroll
        for (int ks = 0; ks < 4; ++ks) {
            const int tl = ks >> 1, k1 = ks & 1;
            unsigned x0 = pw0[tl][2*k1], y0 = pw0[tl][2*k1 + 1];
            unsigned x1 = pw1[tl][2*k1], y1 = pw1[tl][2*k1 + 1];
            asm("v_permlane32_swap_b32 %0, %1" : "+v"(x0), "+v"(y0));
            asm("v_permlane32_swap_b32 %0, %1" : "+v"(x1), "+v"(y1));
            u32x4 fv = {x0, x1, y0, y1};
            s16x8 bP = __builtin_bit_cast(s16x8, fv);
            s16x8 a0 = *(const s16x8*)(vbase + ks*512);
            s16x8 a1 = *(const s16x8*)(vbase + 2048 + ks*512);
            O0 = __builtin_amdgcn_mfma_f32_32x32x16_bf16(a0, bP, O0, 0, 0, 0);
            O1 = __builtin_amdgcn_mfma_f32_32x32x16_bf16(a1, bP, O1, 0, 0, 0);
        }
    }

    // ---- epilogue: O^T rows d = 8u+4hi+{0..3} (+32 for O1), col q=lane&31
    const int qrow = qwi * 32 + r31;
    const size_t gq = (size_t)b*NS + qrow;
    if (outdirect) {
        const float invl = 1.f / l;
        float* orow = outdirect + gq * ND;
        #pragma unroll
        for (int u = 0; u < 4; ++u) {
            const int d0 = 8*u + 4*hi;
            float4 w0v = {O0[4*u]*invl, O0[4*u+1]*invl, O0[4*u+2]*invl, O0[4*u+3]*invl};
            *(float4*)(orow + d0) = w0v;
            float4 w1v = {O1[4*u]*invl, O1[4*u+1]*invl, O1[4*u+2]*invl, O1[4*u+3]*invl};
            *(float4*)(orow + d0 + 32) = w1v;
        }
    } else {
        float* prow = opart + ((size_t)split*NTOK + gq) * ND;
        #pragma unroll
        for (int u = 0; u < 4; ++u) {
            const int d0 = 8*u + 4*hi;
            float4 w0v = {O0[4*u], O0[4*u+1], O0[4*u+2], O0[4*u+3]};
            *(float4*)(prow + d0) = w0v;
            float4 w1v = {O1[4*u], O1[4*u+1], O1[4*u+2], O1[4*u+3]};
            *(float4*)(prow + d0 + 32) = w1v;
        }
        if (lane < 32) lpart[(size_t)split*NTOK + gq] = l;
    }
}

// ---------------------------------------------------------------------------
// Combine KV-split partials (no max tracking): out = sum_s O_s / sum_s l_s
// ---------------------------------------------------------------------------
__global__ __launch_bounds__(256) void combine_kernel(
    const float* __restrict__ opart, const float* __restrict__ lpart,
    float* __restrict__ out, int nsplit)
{
    const int tid = threadIdx.x;
    const int r = blockIdx.x * 16 + (tid >> 4);
    const int c = (tid & 15) * 4;
    float L = 0.f;
    float4 acc = {0.f, 0.f, 0.f, 0.f};
    #pragma unroll
    for (int s = 0; s < 8; ++s) {
        if (s >= nsplit) break;
        L += lpart[(size_t)s*NTOK + r];
        float4 o = *(const float4*)(opart + ((size_t)s*NTOK + r)*ND + c);
        acc.x += o.x; acc.y += o.y; acc.z += o.z; acc.w += o.w;
    }
    const float inv = 1.f / L;
    float4 res = {acc.x*inv, acc.y*inv, acc.z*inv, acc.w*inv};
    *(float4*)(out + (size_t)r*ND + c) = res;
}

extern "C" void kernel_launch(void* const* d_in, const int* in_sizes, int n_in,
                              void* d_out, int out_size, void* d_ws, size_t ws_size,
                              hipStream_t stream) {
    (void)in_sizes; (void)n_in; (void)out_size;
    const float* q  = (const float*)d_in[0];
    const float* k  = (const float*)d_in[1];
    const float* v  = (const float*)d_in[2];
    // d_in[3] = attn_mask (1,1,1): scalar added to all scores -> softmax no-op
    const float* Wq = (const float*)d_in[4];
    const float* bq = (const float*)d_in[5];
    const float* Wk = (const float*)d_in[6];
    const float* bk = (const float*)d_in[7];
    const float* Wv = (const float*)d_in[8];
    const float* bv = (const float*)d_in[9];
    const float* qw = (const float*)d_in[10];
    const float* kw = (const float*)d_in[11];

    __hip_bfloat16* qfb = (__hip_bfloat16*)d_ws;            // 2 MB
    __hip_bfloat16* kfb = qfb + (size_t)NTOK*ND;            // 2 MB
    __hip_bfloat16* vfb = kfb + (size_t)NTOK*ND;            // 2 MB
    float* rest = (float*)(vfb + (size_t)NTOK*ND);

    auto need = [](int s) {
        return (size_t)NTOK*ND*2*3 + (size_t)s*NTOK*(ND*4 + 4);
    };
    const int nsplit = (ws_size >= need(8)) ? 8
                     : (ws_size >= need(4)) ? 4
                     : (ws_size >= need(2)) ? 2 : 1;

    float* opart = rest;
    float* lp = opart + (size_t)nsplit*NTOK*ND;

    proj_kernel<<<dim3(256, 3), 512, 0, stream>>>(q, k, v, Wq, bq, Wk, bk, Wv, bv,
                                                  qw, kw, qfb, kfb, vfb);
    attn_kernel<<<dim3(512*nsplit), 64, 0, stream>>>(
        qfb, kfb, vfb, opart, lp,
        (nsplit == 1) ? (float*)d_out : nullptr, nsplit);
    if (nsplit > 1)
        combine_kernel<<<dim3(NTOK/16), 256, 0, stream>>>(opart, lp,
                                                          (float*)d_out, nsplit);
}

// Round 5
// 125.382 us; speedup vs baseline: 1.9649x; 1.1611x over previous
//
#include <hip/hip_runtime.h>
#include <hip/hip_bf16.h>

typedef __attribute__((ext_vector_type(8)))  short    s16x8;
typedef __attribute__((ext_vector_type(16))) float    f32x16;
typedef __attribute__((ext_vector_type(4)))  unsigned u32x4;

#define NB 4
#define NS 4096
#define ND 64
#define NTOK (NB*NS)
#define PERB (NS*ND)   // elements per batch per tensor

static __device__ __forceinline__ unsigned cvt_pk_bf16(float lo, float hi) {
    unsigned r;
    asm("v_cvt_pk_bf16_f32 %0, %1, %2" : "=v"(r) : "v"(lo), "v"(hi));
    return r;
}
static __device__ __forceinline__ float exp2_fast(float x) {
    float r;
    asm("v_exp_f32 %0, %1" : "=v"(r) : "v"(x));
    return r;
}
static __device__ __forceinline__ short f2bf_s(float x) {
    __hip_bfloat16 h = __float2bfloat16(x);
    return (short)__builtin_bit_cast(unsigned short, h);
}

// ---------------------------------------------------------------------------
// Projection into MFMA-fragment-major layouts (so attn does contiguous 1KB
// wave reads, zero LDS):
//  Q',K' (y=0,1): elem [t=32T+r][d=16c+8hi+j] -> T*2048 + (c*2+hi)*256 + r*8 + j
//  V^T  (y=2):   elem [d=32h+r][t=64TT+16ks+8hi+j]
//                -> TT*4096 + h*2048 + ks*512 + hi*256 + r*8 + j
//  Scales folded: Q' *= qw/64 * LOG2E (attn uses v_exp_f32=2^x), K' *= kw/64.
// 512 threads = 8 waves; wave wv computes outs d=8wv..8wv+7 for rows bx*64+lane.
// KEY (r5): wv forced to SGPR via readfirstlane -> W/bias/scale loads become
// s_load (2KB scalar traffic per wave instead of 128KB per-lane vector traffic
// through L1, which was proj's 41us bottleneck). FMA = v_fmac_f32 v,s,v.
// ---------------------------------------------------------------------------
__global__ __launch_bounds__(512) void proj_kernel(
    const float* __restrict__ q, const float* __restrict__ k, const float* __restrict__ v,
    const float* __restrict__ Wq, const float* __restrict__ bq,
    const float* __restrict__ Wk, const float* __restrict__ bk,
    const float* __restrict__ Wv, const float* __restrict__ bv,
    const float* __restrict__ qw, const float* __restrict__ kw,
    __hip_bfloat16* __restrict__ qf, __hip_bfloat16* __restrict__ kf,
    __hip_bfloat16* __restrict__ vf)
{
    const int which = blockIdx.y;
    const int wv    = __builtin_amdgcn_readfirstlane(threadIdx.x >> 6); // wave-uniform SGPR
    const int lane  = threadIdx.x & 63;
    const int row   = blockIdx.x * 64 + lane;           // b*4096+s
    const float* X    = (which == 0) ? q  : (which == 1) ? k  : v;
    const float* W    = (which == 0) ? Wq : (which == 1) ? Wk : Wv;
    const float* bias = (which == 0) ? bq : (which == 1) ? bk : bv;

    float x[64];
    const float4* xr = (const float4*)(X + (size_t)row * ND);
    #pragma unroll
    for (int i = 0; i < 16; ++i) ((float4*)x)[i] = xr[i];

    float acc8[8];
    #pragma unroll
    for (int dd = 0; dd < 8; ++dd) {
        const float* wr = W + (8*wv + dd) * ND;         // SGPR-uniform -> s_load
        float s = 0.f;
        #pragma unroll
        for (int i = 0; i < 64; ++i) s += x[i] * wr[i];
        acc8[dd] = s + bias[8*wv + dd];
    }

    const int b = row >> 12, t = row & (NS - 1);

    if (which == 2) {
        // V^T frag-major: d = 8wv+dd -> h=wv>>2, r=8*(wv&3)+dd; t -> TT,ks,hi,j
        const size_t base = (size_t)b*PERB + (size_t)(t >> 6)*4096
                          + ((t >> 4) & 3)*512 + ((t >> 3) & 1)*256 + (t & 7)
                          + (wv >> 2)*2048;
        #pragma unroll
        for (int dd = 0; dd < 8; ++dd)
            vf[base + (8*(wv & 3) + dd)*8] = __float2bfloat16(acc8[dd]);
    } else {
        const float* sc = (which == 0) ? qw : kw;       // SGPR-uniform -> s_load
        const float extra = (which == 0) ? 1.44269504088896f : 1.0f; // LOG2E
        s16x8 vch;
        #pragma unroll
        for (int j = 0; j < 8; ++j)
            vch[j] = f2bf_s(acc8[j] * sc[8*wv + j] * 0.015625f * extra);
        __hip_bfloat16* dst = ((which == 0) ? qf : kf)
            + (size_t)b*PERB + (size_t)(t >> 5)*2048 + wv*256 + (t & 31)*8;
        *(s16x8*)dst = vch;
    }
}

// ---------------------------------------------------------------------------
// Flash attention, 1 wave per (32 q-rows, KV-split). ZERO LDS/barriers.
// All K/Q/V fragment loads are contiguous 1KB wave reads (frag-major layout).
// Swapped QK^T: S^T[t][q] = K . Q^T. Softmax WITHOUT max subtraction
// (scores bounded by the 1/d^2 scaling; LOG2E pre-folded into Q').
// P packed to bf16 via cvt_pk + permlane32_swap -> PV B-frags in-register.
// PV: O^T[d][q] = V^T . P^T. Grid: b=bid&3 (XCD-pinned), qwi=(bid>>2)&127,
// split=bid>>9.
// ---------------------------------------------------------------------------
__global__ __launch_bounds__(64, 4) void attn_kernel(
    const __hip_bfloat16* __restrict__ qf, const __hip_bfloat16* __restrict__ kf,
    const __hip_bfloat16* __restrict__ vf,
    float* __restrict__ opart, float* __restrict__ lpart,
    float* __restrict__ outdirect, int nsplit)
{
    const int lane = threadIdx.x;
    const int r31 = lane & 31, hi = lane >> 5;
    const int bid = blockIdx.x;
    const int b     = bid & 3;
    const int qwi   = (bid >> 2) & 127;                 // 128 q-waves per batch
    const int split = bid >> 9;

    const __hip_bfloat16* qb = qf + (size_t)b*PERB;
    const __hip_bfloat16* kb = kf + (size_t)b*PERB;
    const __hip_bfloat16* vb = vf + (size_t)b*PERB;

    // Q B-frags: contiguous 1KB per c
    const __hip_bfloat16* qr = qb + (size_t)qwi*2048 + hi*256 + r31*8;
    s16x8 bQ[4];
    #pragma unroll
    for (int c = 0; c < 4; ++c) bQ[c] = *(const s16x8*)(qr + c*512);

    f32x16 O0 = (f32x16)0.f, O1 = (f32x16)0.f;          // O^T, d-halves
    float l = 0.f;

    const int span  = NS / nsplit;
    const int tbeg  = split * span;
    const int iters = span >> 6;

    for (int it = 0; it < iters; ++it) {
        const int tb = tbeg + (it << 6);

        // ---- QK^T: two 32-row t-tiles, K=64 over 4 mfmas each ----
        const __hip_bfloat16* kbase = kb + (size_t)(tb >> 5)*2048 + hi*256 + r31*8;
        f32x16 s0 = (f32x16)0.f, s1 = (f32x16)0.f;
        #pragma unroll
        for (int c = 0; c < 4; ++c) {
            s16x8 a0 = *(const s16x8*)(kbase + c*512);
            s16x8 a1 = *(const s16x8*)(kbase + 2048 + c*512);
            s0 = __builtin_amdgcn_mfma_f32_32x32x16_bf16(a0, bQ[c], s0, 0, 0, 0);
            s1 = __builtin_amdgcn_mfma_f32_32x32x16_bf16(a1, bQ[c], s1, 0, 0, 0);
        }

        // ---- softmax sans max: p = 2^s (LOG2E folded into Q') ----
        #pragma unroll
        for (int r = 0; r < 16; ++r) { s0[r] = exp2_fast(s0[r]); s1[r] = exp2_fast(s1[r]); }
        // balanced-tree sum of 32 values
        float t0 = ((s0[0]+s0[1])+(s0[2]+s0[3])) + ((s0[4]+s0[5])+(s0[6]+s0[7]));
        float t1 = ((s0[8]+s0[9])+(s0[10]+s0[11])) + ((s0[12]+s0[13])+(s0[14]+s0[15]));
        float t2 = ((s1[0]+s1[1])+(s1[2]+s1[3])) + ((s1[4]+s1[5])+(s1[6]+s1[7]));
        float t3 = ((s1[8]+s1[9])+(s1[10]+s1[11])) + ((s1[12]+s1[13])+(s1[14]+s1[15]));
        float rs = (t0 + t1) + (t2 + t3);
        rs += __shfl_xor(rs, 32);
        l += rs;

        // ---- pack P -> bf16 dwords; permlane32_swap pairs (u=2k1, 2k1+1)
        //      -> B-frag(ks=2*tile+k1) dwords [x0',x1',y0',y1'] ----
        unsigned pw0[2][4], pw1[2][4];
        #pragma unroll
        for (int u = 0; u < 4; ++u) {
            pw0[0][u] = cvt_pk_bf16(s0[4*u],   s0[4*u+1]);
            pw1[0][u] = cvt_pk_bf16(s0[4*u+2], s0[4*u+3]);
            pw0[1][u] = cvt_pk_bf16(s1[4*u],   s1[4*u+1]);
            pw1[1][u] = cvt_pk_bf16(s1[4*u+2], s1[4*u+3]);
        }

        // ---- PV: O^T[d][q] += V^T . P^T  (V frags contiguous 1KB) ----
        const __hip_bfloat16* vbase = vb + (size_t)(tb >> 6)*4096 + hi*256 + r31*8;
        #pragma unroll
        for (int ks = 0; ks < 4; ++ks) {
            const int tl = ks >> 1, k1 = ks & 1;
            unsigned x0 = pw0[tl][2*k1], y0 = pw0[tl][2*k1 + 1];
            unsigned x1 = pw1[tl][2*k1], y1 = pw1[tl][2*k1 + 1];
            asm("v_permlane32_swap_b32 %0, %1" : "+v"(x0), "+v"(y0));
            asm("v_permlane32_swap_b32 %0, %1" : "+v"(x1), "+v"(y1));
            u32x4 fv = {x0, x1, y0, y1};
            s16x8 bP = __builtin_bit_cast(s16x8, fv);
            s16x8 a0 = *(const s16x8*)(vbase + ks*512);
            s16x8 a1 = *(const s16x8*)(vbase + 2048 + ks*512);
            O0 = __builtin_amdgcn_mfma_f32_32x32x16_bf16(a0, bP, O0, 0, 0, 0);
            O1 = __builtin_amdgcn_mfma_f32_32x32x16_bf16(a1, bP, O1, 0, 0, 0);
        }
    }

    // ---- epilogue: O^T rows d = 8u+4hi+{0..3} (+32 for O1), col q=lane&31
    const int qrow = qwi * 32 + r31;
    const size_t gq = (size_t)b*NS + qrow;
    if (outdirect) {
        const float invl = 1.f / l;
        float* orow = outdirect + gq * ND;
        #pragma unroll
        for (int u = 0; u < 4; ++u) {
            const int d0 = 8*u + 4*hi;
            float4 w0v = {O0[4*u]*invl, O0[4*u+1]*invl, O0[4*u+2]*invl, O0[4*u+3]*invl};
            *(float4*)(orow + d0) = w0v;
            float4 w1v = {O1[4*u]*invl, O1[4*u+1]*invl, O1[4*u+2]*invl, O1[4*u+3]*invl};
            *(float4*)(orow + d0 + 32) = w1v;
        }
    } else {
        float* prow = opart + ((size_t)split*NTOK + gq) * ND;
        #pragma unroll
        for (int u = 0; u < 4; ++u) {
            const int d0 = 8*u + 4*hi;
            float4 w0v = {O0[4*u], O0[4*u+1], O0[4*u+2], O0[4*u+3]};
            *(float4*)(prow + d0) = w0v;
            float4 w1v = {O1[4*u], O1[4*u+1], O1[4*u+2], O1[4*u+3]};
            *(float4*)(prow + d0 + 32) = w1v;
        }
        if (lane < 32) lpart[(size_t)split*NTOK + gq] = l;
    }
}

// ---------------------------------------------------------------------------
// Combine KV-split partials (no max tracking): out = sum_s O_s / sum_s l_s
// ---------------------------------------------------------------------------
__global__ __launch_bounds__(256) void combine_kernel(
    const float* __restrict__ opart, const float* __restrict__ lpart,
    float* __restrict__ out, int nsplit)
{
    const int tid = threadIdx.x;
    const int r = blockIdx.x * 16 + (tid >> 4);
    const int c = (tid & 15) * 4;
    float L = 0.f;
    float4 acc = {0.f, 0.f, 0.f, 0.f};
    #pragma unroll
    for (int s = 0; s < 8; ++s) {
        if (s >= nsplit) break;
        L += lpart[(size_t)s*NTOK + r];
        float4 o = *(const float4*)(opart + ((size_t)s*NTOK + r)*ND + c);
        acc.x += o.x; acc.y += o.y; acc.z += o.z; acc.w += o.w;
    }
    const float inv = 1.f / L;
    float4 res = {acc.x*inv, acc.y*inv, acc.z*inv, acc.w*inv};
    *(float4*)(out + (size_t)r*ND + c) = res;
}

extern "C" void kernel_launch(void* const* d_in, const int* in_sizes, int n_in,
                              void* d_out, int out_size, void* d_ws, size_t ws_size,
                              hipStream_t stream) {
    (void)in_sizes; (void)n_in; (void)out_size;
    const float* q  = (const float*)d_in[0];
    const float* k  = (const float*)d_in[1];
    const float* v  = (const float*)d_in[2];
    // d_in[3] = attn_mask (1,1,1): scalar added to all scores -> softmax no-op
    const float* Wq = (const float*)d_in[4];
    const float* bq = (const float*)d_in[5];
    const float* Wk = (const float*)d_in[6];
    const float* bk = (const float*)d_in[7];
    const float* Wv = (const float*)d_in[8];
    const float* bv = (const float*)d_in[9];
    const float* qw = (const float*)d_in[10];
    const float* kw = (const float*)d_in[11];

    __hip_bfloat16* qfb = (__hip_bfloat16*)d_ws;            // 2 MB
    __hip_bfloat16* kfb = qfb + (size_t)NTOK*ND;            // 2 MB
    __hip_bfloat16* vfb = kfb + (size_t)NTOK*ND;            // 2 MB
    float* rest = (float*)(vfb + (size_t)NTOK*ND);

    auto need = [](int s) {
        return (size_t)NTOK*ND*2*3 + (size_t)s*NTOK*(ND*4 + 4);
    };
    const int nsplit = (ws_size >= need(8)) ? 8
                     : (ws_size >= need(4)) ? 4
                     : (ws_size >= need(2)) ? 2 : 1;

    float* opart = rest;
    float* lp = opart + (size_t)nsplit*NTOK*ND;

    proj_kernel<<<dim3(256, 3), 512, 0, stream>>>(q, k, v, Wq, bq, Wk, bk, Wv, bv,
                                                  qw, kw, qfb, kfb, vfb);
    attn_kernel<<<dim3(512*nsplit), 64, 0, stream>>>(
        qfb, kfb, vfb, opart, lp,
        (nsplit == 1) ? (float*)d_out : nullptr, nsplit);
    if (nsplit > 1)
        combine_kernel<<<dim3(NTOK/16), 256, 0, stream>>>(opart, lp,
                                                          (float*)d_out, nsplit);
}

// Round 8
// 115.711 us; speedup vs baseline: 2.1292x; 1.0836x over previous
//
#include <hip/hip_runtime.h>
#include <hip/hip_bf16.h>

typedef __attribute__((ext_vector_type(8)))  short    s16x8;
typedef __attribute__((ext_vector_type(4)))  short    s16x4;
typedef __attribute__((ext_vector_type(16))) float    f32x16;
typedef __attribute__((ext_vector_type(4)))  unsigned u32x4;
typedef __attribute__((ext_vector_type(2)))  unsigned u32x2;

#define NB 4
#define NS 4096
#define ND 64
#define NTOK (NB*NS)
#define PERB (NS*ND)   // elements per batch per tensor

static __device__ __forceinline__ unsigned cvt_pk_bf16(float lo, float hi) {
    unsigned r;
    asm("v_cvt_pk_bf16_f32 %0, %1, %2" : "=v"(r) : "v"(lo), "v"(hi));
    return r;
}
static __device__ __forceinline__ float exp2_fast(float x) {
    float r;
    asm("v_exp_f32 %0, %1" : "=v"(r) : "v"(x));
    return r;
}

// ---------------------------------------------------------------------------
// MFMA projection (r6 version, under single-variable test this round).
// One wave per 32-token tile, all 64 outputs.
//  Layouts produced (exactly what attn reads):
//   Q',K' [t][d]: (t>>5)*2048 + (d>>3)*256 + (t&31)*8 + (d&7)
//   V^T  [d][t]: (t>>6)*4096 + (d>>5)*2048 + ((t>>4)&3)*512 + ((t>>3)&1)*256
//                + (d&31)*8 + (t&7)
//  Scales folded: Q' *= qw/64*LOG2E, K' *= kw/64. Bias added in fp32.
//  which 0/1: acc[dt] = sum_c mfma(wf[dt][c], xf[c])   (D: col=token)
//   C/D: col=lane&31 -> t=bx*32+r31; row=(reg&3)+8*(reg>>2)+4*hi -> d
//   store addr = bx*2048 + (4dt+g)*256 + r31*8 + 4hi + e  (verified = layout)
//  which 2:  acc[nt] = sum_c mfma(xf[c], wf[nt][c])    (D: col=d)
//   store addr = (bx>>1)*4096 + (bx&1)*1024 + nt*2048 + (g>>1)*512
//                + (g&1)*256 + r31*8 + 4hi + e          (verified = layout)
// ---------------------------------------------------------------------------
__global__ __launch_bounds__(64) void proj_kernel(
    const float* __restrict__ q, const float* __restrict__ k, const float* __restrict__ v,
    const float* __restrict__ Wq, const float* __restrict__ bq,
    const float* __restrict__ Wk, const float* __restrict__ bk,
    const float* __restrict__ Wv, const float* __restrict__ bv,
    const float* __restrict__ qw, const float* __restrict__ kw,
    __hip_bfloat16* __restrict__ qf, __hip_bfloat16* __restrict__ kf,
    __hip_bfloat16* __restrict__ vf)
{
    const int which = blockIdx.y;
    const int lane = threadIdx.x;
    const int r31 = lane & 31, hi = lane >> 5;
    const int bx = blockIdx.x;                          // 32-token tile
    const float* X    = (which == 0) ? q  : (which == 1) ? k  : v;
    const float* W    = (which == 0) ? Wq : (which == 1) ? Wk : Wv;
    const float* bias = (which == 0) ? bq : (which == 1) ? bk : bv;

    // X fragments: token = bx*32 + r31, chunk i = 16c+8hi+j
    const float* xrow = X + ((size_t)bx*32 + r31) * ND + 8*hi;
    s16x8 xf[4];
    #pragma unroll
    for (int c = 0; c < 4; ++c) {
        float4 f0 = *(const float4*)(xrow + 16*c);
        float4 f1 = *(const float4*)(xrow + 16*c + 4);
        u32x4 u = { cvt_pk_bf16(f0.x, f0.y), cvt_pk_bf16(f0.z, f0.w),
                    cvt_pk_bf16(f1.x, f1.y), cvt_pk_bf16(f1.z, f1.w) };
        xf[c] = __builtin_bit_cast(s16x8, u);
    }
    // W fragments: row d = 32*dt + r31
    s16x8 wf[2][4];
    #pragma unroll
    for (int dt = 0; dt < 2; ++dt) {
        const float* wrow = W + (size_t)(32*dt + r31) * ND + 8*hi;
        #pragma unroll
        for (int c = 0; c < 4; ++c) {
            float4 f0 = *(const float4*)(wrow + 16*c);
            float4 f1 = *(const float4*)(wrow + 16*c + 4);
            u32x4 u = { cvt_pk_bf16(f0.x, f0.y), cvt_pk_bf16(f0.z, f0.w),
                        cvt_pk_bf16(f1.x, f1.y), cvt_pk_bf16(f1.z, f1.w) };
            wf[dt][c] = __builtin_bit_cast(s16x8, u);
        }
    }

    f32x16 acc0 = (f32x16)0.f, acc1 = (f32x16)0.f;

    if (which == 2) {
        #pragma unroll
        for (int c = 0; c < 4; ++c) {
            acc0 = __builtin_amdgcn_mfma_f32_32x32x16_bf16(xf[c], wf[0][c], acc0, 0, 0, 0);
            acc1 = __builtin_amdgcn_mfma_f32_32x32x16_bf16(xf[c], wf[1][c], acc1, 0, 0, 0);
        }
        // acc0[4g+e] = vp[t = bx*32 + 8g+4hi+e][d = r31]; acc1 -> d = 32+r31
        const float b0 = bias[r31], b1 = bias[32 + r31];
        __hip_bfloat16* dst = vf + (size_t)(bx >> 1)*4096 + (bx & 1)*1024
                                 + r31*8 + 4*hi;
        #pragma unroll
        for (int g = 0; g < 4; ++g) {
            u32x2 p0 = { cvt_pk_bf16(acc0[4*g]   + b0, acc0[4*g+1] + b0),
                         cvt_pk_bf16(acc0[4*g+2] + b0, acc0[4*g+3] + b0) };
            *(s16x4*)(dst + (g >> 1)*512 + (g & 1)*256) = __builtin_bit_cast(s16x4, p0);
            u32x2 p1 = { cvt_pk_bf16(acc1[4*g]   + b1, acc1[4*g+1] + b1),
                         cvt_pk_bf16(acc1[4*g+2] + b1, acc1[4*g+3] + b1) };
            *(s16x4*)(dst + 2048 + (g >> 1)*512 + (g & 1)*256) = __builtin_bit_cast(s16x4, p1);
        }
    } else {
        #pragma unroll
        for (int c = 0; c < 4; ++c) {
            acc0 = __builtin_amdgcn_mfma_f32_32x32x16_bf16(wf[0][c], xf[c], acc0, 0, 0, 0);
            acc1 = __builtin_amdgcn_mfma_f32_32x32x16_bf16(wf[1][c], xf[c], acc1, 0, 0, 0);
        }
        // acc_dt[4g+e] = qp[t = bx*32+r31][d = 32dt+8g+4hi+e]
        const float* sc = (which == 0) ? qw : kw;
        const float cf = (which == 0) ? (0.015625f * 1.44269504088896f) : 0.015625f;
        __hip_bfloat16* dst = ((which == 0) ? qf : kf) + (size_t)bx*2048 + r31*8 + 4*hi;
        #pragma unroll
        for (int dt = 0; dt < 2; ++dt) {
            const f32x16 acc = dt ? acc1 : acc0;
            #pragma unroll
            for (int g = 0; g < 4; ++g) {
                const int dbase = 32*dt + 8*g + 4*hi;
                float4 b4 = *(const float4*)(bias + dbase);
                float4 s4 = *(const float4*)(sc + dbase);
                float v0 = (acc[4*g+0] + b4.x) * (s4.x * cf);
                float v1 = (acc[4*g+1] + b4.y) * (s4.y * cf);
                float v2 = (acc[4*g+2] + b4.z) * (s4.z * cf);
                float v3 = (acc[4*g+3] + b4.w) * (s4.w * cf);
                u32x2 p = { cvt_pk_bf16(v0, v1), cvt_pk_bf16(v2, v3) };
                *(s16x4*)(dst + (4*dt + g)*256) = __builtin_bit_cast(s16x4, p);
            }
        }
    }
}

// ---------------------------------------------------------------------------
// Flash attention — r5 version, BYTE-IDENTICAL (known-good, absmax 2.44e-4).
// 1 wave per (32 q-rows, KV-split). ZERO LDS/barriers. Frag-major loads.
// Swapped QK^T (S^T = K.Q^T), softmax without max, cvt_pk+permlane32_swap
// P pack. Grid = 512*nsplit: b=bid&3, qwi=(bid>>2)&127, split=bid>>9.
// ---------------------------------------------------------------------------
__global__ __launch_bounds__(64, 4) void attn_kernel(
    const __hip_bfloat16* __restrict__ qf, const __hip_bfloat16* __restrict__ kf,
    const __hip_bfloat16* __restrict__ vf,
    float* __restrict__ opart, float* __restrict__ lpart,
    float* __restrict__ outdirect, int nsplit)
{
    const int lane = threadIdx.x;
    const int r31 = lane & 31, hi = lane >> 5;
    const int bid = blockIdx.x;
    const int b     = bid & 3;
    const int qwi   = (bid >> 2) & 127;                 // 128 q-waves per batch
    const int split = bid >> 9;

    const __hip_bfloat16* qb = qf + (size_t)b*PERB;
    const __hip_bfloat16* kb = kf + (size_t)b*PERB;
    const __hip_bfloat16* vb = vf + (size_t)b*PERB;

    // Q B-frags: contiguous 1KB per c
    const __hip_bfloat16* qr = qb + (size_t)qwi*2048 + hi*256 + r31*8;
    s16x8 bQ[4];
    #pragma unroll
    for (int c = 0; c < 4; ++c) bQ[c] = *(const s16x8*)(qr + c*512);

    f32x16 O0 = (f32x16)0.f, O1 = (f32x16)0.f;          // O^T, d-halves
    float l = 0.f;

    const int span  = NS / nsplit;
    const int tbeg  = split * span;
    const int iters = span >> 6;

    for (int it = 0; it < iters; ++it) {
        const int tb = tbeg + (it << 6);

        // ---- QK^T: two 32-row t-tiles, K=64 over 4 mfmas each ----
        const __hip_bfloat16* kbase = kb + (size_t)(tb >> 5)*2048 + hi*256 + r31*8;
        f32x16 s0 = (f32x16)0.f, s1 = (f32x16)0.f;
        #pragma unroll
        for (int c = 0; c < 4; ++c) {
            s16x8 a0 = *(const s16x8*)(kbase + c*512);
            s16x8 a1 = *(const s16x8*)(kbase + 2048 + c*512);
            s0 = __builtin_amdgcn_mfma_f32_32x32x16_bf16(a0, bQ[c], s0, 0, 0, 0);
            s1 = __builtin_amdgcn_mfma_f32_32x32x16_bf16(a1, bQ[c], s1, 0, 0, 0);
        }

        // ---- p = 2^s (LOG2E folded into Q'), row-sum ----
        #pragma unroll
        for (int r = 0; r < 16; ++r) { s0[r] = exp2_fast(s0[r]); s1[r] = exp2_fast(s1[r]); }
        float t0 = ((s0[0]+s0[1])+(s0[2]+s0[3])) + ((s0[4]+s0[5])+(s0[6]+s0[7]));
        float t1 = ((s0[8]+s0[9])+(s0[10]+s0[11])) + ((s0[12]+s0[13])+(s0[14]+s0[15]));
        float t2 = ((s1[0]+s1[1])+(s1[2]+s1[3])) + ((s1[4]+s1[5])+(s1[6]+s1[7]));
        float t3 = ((s1[8]+s1[9])+(s1[10]+s1[11])) + ((s1[12]+s1[13])+(s1[14]+s1[15]));
        float rs = (t0 + t1) + (t2 + t3);
        rs += __shfl_xor(rs, 32);
        l += rs;

        // ---- pack P -> bf16 dwords; permlane32_swap pairs (u=2k1, 2k1+1)
        //      -> B-frag(ks=2*tile+k1) dwords [x0',x1',y0',y1'] ----
        unsigned pw0[2][4], pw1[2][4];
        #pragma unroll
        for (int u = 0; u < 4; ++u) {
            pw0[0][u] = cvt_pk_bf16(s0[4*u],   s0[4*u+1]);
            pw1[0][u] = cvt_pk_bf16(s0[4*u+2], s0[4*u+3]);
            pw0[1][u] = cvt_pk_bf16(s1[4*u],   s1[4*u+1]);
            pw1[1][u] = cvt_pk_bf16(s1[4*u+2], s1[4*u+3]);
        }

        // ---- PV: O^T[d][q] += V^T . P^T  (V frags contiguous 1KB) ----
        const __hip_bfloat16* vbase = vb + (size_t)(tb >> 6)*4096 + hi*256 + r31*8;
        #pragma unroll
        for (int ks = 0; ks < 4; ++ks) {
            const int tl = ks >> 1, k1 = ks & 1;
            unsigned x0 = pw0[tl][2*k1], y0 = pw0[tl][2*k1 + 1];
            unsigned x1 = pw1[tl][2*k1], y1 = pw1[tl][2*k1 + 1];
            asm("v_permlane32_swap_b32 %0, %1" : "+v"(x0), "+v"(y0));
            asm("v_permlane32_swap_b32 %0, %1" : "+v"(x1), "+v"(y1));
            u32x4 fv = {x0, x1, y0, y1};
            s16x8 bP = __builtin_bit_cast(s16x8, fv);
            s16x8 a0 = *(const s16x8*)(vbase + ks*512);
            s16x8 a1 = *(const s16x8*)(vbase + 2048 + ks*512);
            O0 = __builtin_amdgcn_mfma_f32_32x32x16_bf16(a0, bP, O0, 0, 0, 0);
            O1 = __builtin_amdgcn_mfma_f32_32x32x16_bf16(a1, bP, O1, 0, 0, 0);
        }
    }

    // ---- epilogue: O^T rows d = 8u+4hi+{0..3} (+32 for O1), col q=lane&31
    const int qrow = qwi * 32 + r31;
    const size_t gq = (size_t)b*NS + qrow;
    if (outdirect) {
        const float invl = 1.f / l;
        float* orow = outdirect + gq * ND;
        #pragma unroll
        for (int u = 0; u < 4; ++u) {
            const int d0 = 8*u + 4*hi;
            float4 w0v = {O0[4*u]*invl, O0[4*u+1]*invl, O0[4*u+2]*invl, O0[4*u+3]*invl};
            *(float4*)(orow + d0) = w0v;
            float4 w1v = {O1[4*u]*invl, O1[4*u+1]*invl, O1[4*u+2]*invl, O1[4*u+3]*invl};
            *(float4*)(orow + d0 + 32) = w1v;
        }
    } else {
        float* prow = opart + ((size_t)split*NTOK + gq) * ND;
        #pragma unroll
        for (int u = 0; u < 4; ++u) {
            const int d0 = 8*u + 4*hi;
            float4 w0v = {O0[4*u], O0[4*u+1], O0[4*u+2], O0[4*u+3]};
            *(float4*)(prow + d0) = w0v;
            float4 w1v = {O1[4*u], O1[4*u+1], O1[4*u+2], O1[4*u+3]};
            *(float4*)(prow + d0 + 32) = w1v;
        }
        if (lane < 32) lpart[(size_t)split*NTOK + gq] = l;
    }
}

// ---------------------------------------------------------------------------
// Combine KV-split partials (no max tracking): out = sum_s O_s / sum_s l_s
// ---------------------------------------------------------------------------
__global__ __launch_bounds__(256) void combine_kernel(
    const float* __restrict__ opart, const float* __restrict__ lpart,
    float* __restrict__ out, int nsplit)
{
    const int tid = threadIdx.x;
    const int r = blockIdx.x * 16 + (tid >> 4);
    const int c = (tid & 15) * 4;
    float L = 0.f;
    float4 acc = {0.f, 0.f, 0.f, 0.f};
    #pragma unroll
    for (int s = 0; s < 8; ++s) {
        if (s >= nsplit) break;
        L += lpart[(size_t)s*NTOK + r];
        float4 o = *(const float4*)(opart + ((size_t)s*NTOK + r)*ND + c);
        acc.x += o.x; acc.y += o.y; acc.z += o.z; acc.w += o.w;
    }
    const float inv = 1.f / L;
    float4 res = {acc.x*inv, acc.y*inv, acc.z*inv, acc.w*inv};
    *(float4*)(out + (size_t)r*ND + c) = res;
}

extern "C" void kernel_launch(void* const* d_in, const int* in_sizes, int n_in,
                              void* d_out, int out_size, void* d_ws, size_t ws_size,
                              hipStream_t stream) {
    (void)in_sizes; (void)n_in; (void)out_size;
    const float* q  = (const float*)d_in[0];
    const float* k  = (const float*)d_in[1];
    const float* v  = (const float*)d_in[2];
    // d_in[3] = attn_mask (1,1,1): scalar added to all scores -> softmax no-op
    const float* Wq = (const float*)d_in[4];
    const float* bq = (const float*)d_in[5];
    const float* Wk = (const float*)d_in[6];
    const float* bk = (const float*)d_in[7];
    const float* Wv = (const float*)d_in[8];
    const float* bv = (const float*)d_in[9];
    const float* qw = (const float*)d_in[10];
    const float* kw = (const float*)d_in[11];

    __hip_bfloat16* qfb = (__hip_bfloat16*)d_ws;            // 2 MB
    __hip_bfloat16* kfb = qfb + (size_t)NTOK*ND;            // 2 MB
    __hip_bfloat16* vfb = kfb + (size_t)NTOK*ND;            // 2 MB
    float* rest = (float*)(vfb + (size_t)NTOK*ND);

    auto need = [](int s) {
        return (size_t)NTOK*ND*2*3 + (size_t)s*NTOK*(ND*4 + 4);
    };
    const int nsplit = (ws_size >= need(8)) ? 8
                     : (ws_size >= need(4)) ? 4
                     : (ws_size >= need(2)) ? 2 : 1;

    float* opart = rest;
    float* lp = opart + (size_t)nsplit*NTOK*ND;

    proj_kernel<<<dim3(512, 3), 64, 0, stream>>>(q, k, v, Wq, bq, Wk, bk, Wv, bv,
                                                 qw, kw, qfb, kfb, vfb);
    attn_kernel<<<dim3(512*nsplit), 64, 0, stream>>>(
        qfb, kfb, vfb, opart, lp,
        (nsplit == 1) ? (float*)d_out : nullptr, nsplit);
    if (nsplit > 1)
        combine_kernel<<<dim3(NTOK/16), 256, 0, stream>>>(opart, lp,
                                                          (float*)d_out, nsplit);
}